// Round 6
// baseline (3217.769 us; speedup 1.0000x reference)
//
#include <hip/hip_runtime.h>
#include <hip/hip_bf16.h>

// LSTM: L=512 steps, N=64 batch, I=H=1024.
// Round 6: SENTINEL-SYNCED ring. Ring slots 1..512 pre-poisoned (0xAAAAAAAA).
// Producer publishes h by simply firing sc1 stores (write-through to the
// coherence point) -- NO vmcnt drain, NO flags. Consumer loads h fragments
// and treats any poison dword as "not yet"; retries via sc0+sc1 loads that
// bypass L1/L2 and read the coherence point. Write-once slots => no stale
// data possible; dword-atomic stores => any non-poison dword is final.
//  K1: convert x fp32->bf16 packed + h0 packed slot 0 + ring poison + flags.
//  K2: persistent recurrence, 128 WGs x 256 thr: register-resident weights,
//      per-wave K-quarter, zero fences, zero flags (RING path).
//  K3: y = h @ W_out^T + b_out.
// Packed slab [64x1024]: elem(row,col) -> byte (col>>3)*1024 + row*16 + (col&7)*2

#define L_STEPS 512
#define NB 64
#define HID 1024
#define GRID_LSTM 128
#define PZN 0xAAAAAAAAu

typedef __bf16 bf16x8 __attribute__((ext_vector_type(8)));
typedef __bf16 bf16x4 __attribute__((ext_vector_type(4)));
typedef __bf16 bf16x2 __attribute__((ext_vector_type(2)));
typedef float  f32x4  __attribute__((ext_vector_type(4)));
typedef float  f32x2  __attribute__((ext_vector_type(2)));
typedef unsigned u32x4 __attribute__((ext_vector_type(4)));

__device__ __forceinline__ float sigmoid_f(float x) {
    return 1.f / (1.f + __expf(-x));
}
__device__ __forceinline__ float tanh_f(float x) {
    return 1.f - 2.f / (1.f + __expf(2.f * x));
}

__global__ void convert_kernel(const float* __restrict__ x, const float* __restrict__ h0,
                               __bf16* __restrict__ xbf, __bf16* __restrict__ hbf,
                               unsigned* __restrict__ bar, int ring) {
    unsigned u = blockIdx.x * 256u + threadIdx.x;
    if (u < 512u) bar[u] = 0u;
    const int row = u & 63;
    const int cg  = (u >> 6) & 127;
    if (u < 8192u) {   // h0 -> packed slot 0
        const float* s = h0 + (size_t)row * HID + cg * 8;
        f32x4 a = *(const f32x4*)s, b = *(const f32x4*)(s + 4);
        bf16x8 o;
        o[0]=(__bf16)a[0]; o[1]=(__bf16)a[1]; o[2]=(__bf16)a[2]; o[3]=(__bf16)a[3];
        o[4]=(__bf16)b[0]; o[5]=(__bf16)b[1]; o[6]=(__bf16)b[2]; o[7]=(__bf16)b[3];
        ((bf16x8*)hbf)[u] = o;
    }
    if (ring) {        // poison ring slots 1..512 (one 16B unit per thread)
        u32x4 P = {PZN, PZN, PZN, PZN};
        ((u32x4*)(hbf + NB * HID))[u] = P;
    }
    const int t = u >> 13;
    const float* s = x + ((size_t)t * NB + row) * HID + cg * 8;
    f32x4 a = *(const f32x4*)s, b = *(const f32x4*)(s + 4);
    bf16x8 o;
    o[0]=(__bf16)a[0]; o[1]=(__bf16)a[1]; o[2]=(__bf16)a[2]; o[3]=(__bf16)a[3];
    o[4]=(__bf16)b[0]; o[5]=(__bf16)b[1]; o[6]=(__bf16)b[2]; o[7]=(__bf16)b[3];
    ((bf16x8*)xbf)[u] = o;
}

// x half-phase on a packed slab. Frag (kk,nt) = act + kk*2048 + nt*128.
__device__ __forceinline__ void mfma_x(const __bf16* __restrict__ act,
                                       const bf16x8 (&wfr)[2][8],
                                       f32x4 (&acc)[2][4]) {
    #pragma unroll
    for (int kk = 0; kk < 8; ++kk) {
        bf16x8 bfr[4];
        #pragma unroll
        for (int nt = 0; nt < 4; ++nt)
            bfr[nt] = *(const bf16x8*)(act + kk * 2048 + nt * 128);
        #pragma unroll
        for (int mt = 0; mt < 2; ++mt)
            #pragma unroll
            for (int nt = 0; nt < 4; ++nt)
                acc[mt][nt] = __builtin_amdgcn_mfma_f32_16x16x32_bf16(
                    wfr[mt][kk], bfr[nt], acc[mt][nt], 0, 0, 0);
    }
}

template <int K0>
__device__ __forceinline__ unsigned pmask16(const u32x4 (&hb)[8][4]) {
    unsigned bad = 0u;
    #pragma unroll
    for (int kk = K0; kk < K0 + 4; ++kk)
        #pragma unroll
        for (int nt = 0; nt < 4; ++nt) {
            const u32x4 v = hb[kk][nt];
            bad |= (unsigned)(v[0] == PZN);
            bad |= (unsigned)(v[1] == PZN);
            bad |= (unsigned)(v[2] == PZN);
            bad |= (unsigned)(v[3] == PZN);
        }
    return bad;
}

template <int K0>
__device__ __forceinline__ void reload16(u32x4 (&hb)[8][4], const __bf16* hb_base) {
    #pragma unroll
    for (int kk = K0; kk < K0 + 4; ++kk)
        #pragma unroll
        for (int nt = 0; nt < 4; ++nt) {
            const __bf16* p = hb_base + kk * 2048 + nt * 128;
            asm volatile("global_load_dwordx4 %0, %1, off sc0 sc1"
                         : "=v"(hb[kk][nt]) : "v"(p));
        }
}

#define WAITDEP16(N, B)                                                        \
    asm volatile("s_waitcnt vmcnt(" #N ")"                                     \
        : "+v"(hb[B+0][0]), "+v"(hb[B+0][1]), "+v"(hb[B+0][2]), "+v"(hb[B+0][3]),\
          "+v"(hb[B+1][0]), "+v"(hb[B+1][1]), "+v"(hb[B+1][2]), "+v"(hb[B+1][3]),\
          "+v"(hb[B+2][0]), "+v"(hb[B+2][1]), "+v"(hb[B+2][2]), "+v"(hb[B+2][3]),\
          "+v"(hb[B+3][0]), "+v"(hb[B+3][1]), "+v"(hb[B+3][2]), "+v"(hb[B+3][3]))

template <bool RING>
__global__ __launch_bounds__(256, 1) void lstm_kernel(
    const float* __restrict__ c0,
    const float* __restrict__ W_ih, const float* __restrict__ W_hh,
    const float* __restrict__ b_ih, const float* __restrict__ b_hh,
    const __bf16* __restrict__ xbf,      // [512] packed 64x1024 slabs
    __bf16* hbuf,                        // RING: [513] slots, else [2] parity
    unsigned* bar,                       // [512] per-wave flags (fallback only)
    float* __restrict__ out)             // d_out: y[65536], h[65536], c[65536]
{
    const int tid  = threadIdx.x;
    const int lane = tid & 63;
    const int w    = tid >> 6;           // wave id: combined-K quarter
    const int quad = lane >> 4;
    const int l15  = lane & 15;
    const int hbase = blockIdx.x * 8;

    __shared__ float red[4][64][44];     // [wave][batch][row pad 32->44] = 45056 B

    // ---- weight preload (once, from row-major fp32 W).
    bf16x8 wfx[2][8], wfh[2][8];
    #pragma unroll
    for (int mt = 0; mt < 2; ++mt) {
        const int n    = mt * 16 + l15;
        const int grow = (n >> 3) * HID + hbase + (n & 7);
        #pragma unroll
        for (int kk = 0; kk < 8; ++kk) {
            const int kcol = w * 256 + kk * 32 + quad * 8;
            {
                const float* src = W_ih + (size_t)grow * 1024 + kcol;
                f32x4 a = *(const f32x4*)src;
                f32x4 b = *(const f32x4*)(src + 4);
                bf16x8 f;
                f[0]=(__bf16)a[0]; f[1]=(__bf16)a[1]; f[2]=(__bf16)a[2]; f[3]=(__bf16)a[3];
                f[4]=(__bf16)b[0]; f[5]=(__bf16)b[1]; f[6]=(__bf16)b[2]; f[7]=(__bf16)b[3];
                wfx[mt][kk] = f;
            }
            {
                const float* src = W_hh + (size_t)grow * 1024 + kcol;
                f32x4 a = *(const f32x4*)src;
                f32x4 b = *(const f32x4*)(src + 4);
                bf16x8 f;
                f[0]=(__bf16)a[0]; f[1]=(__bf16)a[1]; f[2]=(__bf16)a[2]; f[3]=(__bf16)a[3];
                f[4]=(__bf16)b[0]; f[5]=(__bf16)b[1]; f[6]=(__bf16)b[2]; f[7]=(__bf16)b[3];
                wfh[mt][kk] = f;
            }
        }
    }

    // per-thread cell state: pairs (cb, cu) and (cb, cu+1)
    const int p0 = tid * 2;
    const int cb = p0 >> 3;
    const int cu = p0 & 7;
    float c0v = c0[cb * HID + hbase + cu];
    float c1v = c0[cb * HID + hbase + cu + 1];

    float bias0[4], bias1[4];
    #pragma unroll
    for (int gate = 0; gate < 4; ++gate) {
        int gr = gate * HID + hbase + cu;
        bias0[gate] = b_ih[gr] + b_hh[gr];
        bias1[gate] = b_ih[gr + 1] + b_hh[gr + 1];
    }

    // per-lane packed-slab offset (elements)
    const int lane_off = (32 * w + quad) * 512 + l15 * 8;
    // packed h store offset (elements): cg = blockIdx, row = cb, col&7 = cu
    const int hstore_off = blockIdx.x * 512 + cb * 8 + cu;

    // prologue: x-partials for t=0
    f32x4 acc[2][4];
    #pragma unroll
    for (int mt = 0; mt < 2; ++mt)
        #pragma unroll
        for (int nt = 0; nt < 4; ++nt) { f32x4 z = {0.f,0.f,0.f,0.f}; acc[mt][nt] = z; }
    mfma_x(xbf + lane_off, wfx, acc);

    // fallback producer flag set (RING=false only)
    const int pf0 = 128 * w + lane;
    const int pf1 = 128 * w + 64 + lane;

    for (int t = 0; t < L_STEPS; ++t) {
        if constexpr (!RING) {
            for (;;) {
                unsigned f0 = __hip_atomic_load(&bar[pf0], __ATOMIC_RELAXED,
                                                __HIP_MEMORY_SCOPE_AGENT);
                unsigned f1 = __hip_atomic_load(&bar[pf1], __ATOMIC_RELAXED,
                                                __HIP_MEMORY_SCOPE_AGENT);
                if (__all((f0 >= (unsigned)t) && (f1 >= (unsigned)t))) break;
                __builtin_amdgcn_s_sleep(1);
            }
        }

        // ---- h half: 32 fragment loads (1KB contiguous each).
        u32x4 hb[8][4];
        const __bf16* hb_base = hbuf
            + (size_t)(RING ? t : (t & 1)) * (NB * HID) + lane_off;
        #pragma unroll
        for (int kk = 0; kk < 8; ++kk)
            #pragma unroll
            for (int nt = 0; nt < 4; ++nt) {
                const __bf16* p = hb_base + kk * 2048 + nt * 128;
                if constexpr (RING)
                    asm volatile("global_load_dwordx4 %0, %1, off"
                                 : "=v"(hb[kk][nt]) : "v"(p));
                else
                    asm volatile("global_load_dwordx4 %0, %1, off sc1"
                                 : "=v"(hb[kk][nt]) : "v"(p));
            }
        // batch 1: kk 0..3
        WAITDEP16(16, 0);
        if constexpr (RING) {
            unsigned bad = pmask16<0>(hb);
            while (__any((int)bad)) {
                __builtin_amdgcn_s_sleep(1);
                reload16<0>(hb, hb_base);
                WAITDEP16(0, 0);
                bad = pmask16<0>(hb);
            }
        }
        #pragma unroll
        for (int kk = 0; kk < 4; ++kk)
            #pragma unroll
            for (int mt = 0; mt < 2; ++mt)
                #pragma unroll
                for (int nt = 0; nt < 4; ++nt)
                    acc[mt][nt] = __builtin_amdgcn_mfma_f32_16x16x32_bf16(
                        wfh[mt][kk], __builtin_bit_cast(bf16x8, hb[kk][nt]),
                        acc[mt][nt], 0, 0, 0);
        // batch 2: kk 4..7
        WAITDEP16(0, 4);
        if constexpr (RING) {
            unsigned bad = pmask16<4>(hb);
            while (__any((int)bad)) {
                __builtin_amdgcn_s_sleep(1);
                reload16<4>(hb, hb_base);
                WAITDEP16(0, 4);
                bad = pmask16<4>(hb);
            }
        }
        #pragma unroll
        for (int kk = 4; kk < 8; ++kk)
            #pragma unroll
            for (int mt = 0; mt < 2; ++mt)
                #pragma unroll
                for (int nt = 0; nt < 4; ++nt)
                    acc[mt][nt] = __builtin_amdgcn_mfma_f32_16x16x32_bf16(
                        wfh[mt][kk], __builtin_bit_cast(bf16x8, hb[kk][nt]),
                        acc[mt][nt], 0, 0, 0);

        // ---- WAR barrier: prior step's gate reads done before red overwrite
        __syncthreads();

        // partials -> LDS. C/D layout: col = lane&15 (batch), row = quad*4+reg.
        #pragma unroll
        for (int mt = 0; mt < 2; ++mt)
            #pragma unroll
            for (int nt = 0; nt < 4; ++nt) {
                const int row0 = mt * 16 + quad * 4;
                const int col  = nt * 16 + l15;
                *(f32x4*)&red[w][col][row0] = acc[mt][nt];
            }
        __syncthreads();

        // ---- gate phase
        float h0v, h1v;
        {
            float z0[4], z1[4];
            #pragma unroll
            for (int gate = 0; gate < 4; ++gate) {
                const int row = gate * 8 + cu;
                f32x2 s0 = *(const f32x2*)&red[0][cb][row];
                f32x2 s1 = *(const f32x2*)&red[1][cb][row];
                f32x2 s2 = *(const f32x2*)&red[2][cb][row];
                f32x2 s3 = *(const f32x2*)&red[3][cb][row];
                z0[gate] = s0[0] + s1[0] + s2[0] + s3[0] + bias0[gate];
                z1[gate] = s0[1] + s1[1] + s2[1] + s3[1] + bias1[gate];
            }
            float ig = sigmoid_f(z0[0]), fg = sigmoid_f(z0[1]);
            float gg = tanh_f(z0[2]),    og = sigmoid_f(z0[3]);
            c0v = fg * c0v + ig * gg;
            h0v = og * tanh_f(c0v);
            ig = sigmoid_f(z1[0]); fg = sigmoid_f(z1[1]);
            gg = tanh_f(z1[2]);    og = sigmoid_f(z1[3]);
            c1v = fg * c1v + ig * gg;
            h1v = og * tanh_f(c1v);
        }

        // ---- publish h_{t+1}: sc1 store to coherence point. RING: the data
        // itself is the signal -- no drain, no flag, producer moves on.
        {
            bf16x2 hv; hv[0] = (__bf16)h0v; hv[1] = (__bf16)h1v;
            unsigned hbits = __builtin_bit_cast(unsigned, hv);
            const __bf16* dst = hbuf
                + (size_t)(RING ? (t + 1) : ((t + 1) & 1)) * (NB * HID) + hstore_off;
            asm volatile("global_store_dword %0, %1, off sc1"
                         :: "v"(dst), "v"(hbits) : "memory");
        }
        if (t == L_STEPS - 1) {
            const int idx = cb * HID + hbase + cu;
            out[65536 + idx]      = h0v;
            out[65536 + idx + 1]  = h1v;
            out[131072 + idx]     = c0v;
            out[131072 + idx + 1] = c1v;
        }
        if constexpr (!RING) {
            asm volatile("s_waitcnt vmcnt(0)" ::: "memory");
            if (lane == 0)
                __hip_atomic_store(&bar[blockIdx.x * 4 + w], (unsigned)(t + 1),
                                   __ATOMIC_RELAXED, __HIP_MEMORY_SCOPE_AGENT);
        }

        // ---- x half for t+1 (fills the publish->consume transit window)
        #pragma unroll
        for (int mt = 0; mt < 2; ++mt)
            #pragma unroll
            for (int nt = 0; nt < 4; ++nt) { f32x4 z = {0.f,0.f,0.f,0.f}; acc[mt][nt] = z; }
        if (t < L_STEPS - 1)
            mfma_x(xbf + (size_t)(t + 1) * (NB * HID) + lane_off, wfx, acc);
    }
}

__global__ void out_kernel(const float* __restrict__ base, const float* __restrict__ Wout,
                           const float* __restrict__ bout, float* __restrict__ y)
{
    const int wv   = (int)((blockIdx.x * 256u + threadIdx.x) >> 6);
    const int lane = threadIdx.x & 63;
    const int b = wv >> 10;
    const int i = wv & 1023;
    const f32x4* hp = (const f32x4*)(base + 65536 + b * HID);
    const f32x4* wp = (const f32x4*)(Wout + (size_t)i * HID);
    float acc = 0.f;
    #pragma unroll
    for (int q = 0; q < 4; ++q) {
        f32x4 hv = hp[q * 64 + lane];
        f32x4 wvv = wp[q * 64 + lane];
        acc += hv[0]*wvv[0] + hv[1]*wvv[1] + hv[2]*wvv[2] + hv[3]*wvv[3];
    }
    #pragma unroll
    for (int off = 32; off > 0; off >>= 1) acc += __shfl_down(acc, off);
    if (lane == 0) y[b * HID + i] = acc + bout[i];
}

extern "C" void kernel_launch(void* const* d_in, const int* in_sizes, int n_in,
                              void* d_out, int out_size, void* d_ws, size_t ws_size,
                              hipStream_t stream)
{
    const float* x    = (const float*)d_in[0];
    const float* h0   = (const float*)d_in[1];
    const float* c0   = (const float*)d_in[2];
    const float* W_ih = (const float*)d_in[3];
    const float* W_hh = (const float*)d_in[4];
    const float* b_ih = (const float*)d_in[5];
    const float* b_hh = (const float*)d_in[6];
    const float* Wout = (const float*)d_in[7];
    const float* bout = (const float*)d_in[8];
    float* out = (float*)d_out;

    // ws layout: xbf (64 MB) | hbuf (ring: 513 slots = 64.1 MB, else 256 KB) | bar
    const size_t XBF_B  = 67108864;                  // 512 x 131072
    const size_t RING_B = 513ull * 131072;           // 67,239,936
    const size_t need_ring = XBF_B + RING_B + 2048;
    const bool ring = ws_size >= need_ring;

    char* ws = (char*)d_ws;
    __bf16* xbf   = (__bf16*)(ws);
    __bf16* hbuf  = (__bf16*)(ws + XBF_B);
    unsigned* bar = (unsigned*)(ws + XBF_B + (ring ? RING_B : 262144));

    convert_kernel<<<16384, 256, 0, stream>>>(x, h0, xbf, hbuf, bar, (int)ring);
    if (ring)
        lstm_kernel<true><<<GRID_LSTM, 256, 0, stream>>>(c0, W_ih, W_hh, b_ih, b_hh,
                                                         xbf, hbuf, bar, out);
    else
        lstm_kernel<false><<<GRID_LSTM, 256, 0, stream>>>(c0, W_ih, W_hh, b_ih, b_hh,
                                                          xbf, hbuf, bar, out);
    out_kernel<<<16384, 256, 0, stream>>>(out, Wout, bout, out);
}